// Round 1
// baseline (16677.007 us; speedup 1.0000x reference)
//
#include <hip/hip_runtime.h>
#include <math.h>

#define BM 128
#define BN 128
#define BK 16

// C[M,N] = A[M,K] @ B[N,K]^T   (row-major, all dims multiples of tile sizes)
// EPI==0: C = acc
// EPI==1: C = (E - acc)^2   (E read at same coords; in-place with C allowed)
// blockIdx.z batches heads via element strides sA/sB/sC (sA==0 -> shared A, etc.)
template<int EPI>
__global__ __launch_bounds__(256)
void gemm_abt(const float* __restrict__ A, const float* __restrict__ B,
              float* __restrict__ C, const float* __restrict__ E,
              int M, int N, int K,
              long long sA, long long sB, long long sC)
{
    const long long z = blockIdx.z;
    A += z * sA;
    B += z * sB;
    C += z * sC;
    if (EPI == 1) E += z * sC;

    __shared__ float As[BK][BM + 4];
    __shared__ float Bs[BK][BN + 4];

    const int tid = threadIdx.x;          // 0..255
    const int tx  = tid & 15;             // output col group
    const int ty  = tid >> 4;             // output row group

    // staging: each thread loads 8 contiguous K-floats of one A row and one B row
    const int  mrow = tid >> 1;           // 0..127
    const int  kOff = (tid & 1) * 8;      // 0 or 8
    const float* Ag = A + ((long long)blockIdx.y * BM + mrow) * K + kOff;
    const float* Bg = B + ((long long)blockIdx.x * BN + mrow) * K + kOff;

    float acc[8][8];
#pragma unroll
    for (int i = 0; i < 8; i++)
#pragma unroll
        for (int j = 0; j < 8; j++) acc[i][j] = 0.f;

    for (int k0 = 0; k0 < K; k0 += BK) {
        const float4 a0 = *(const float4*)(Ag + k0);
        const float4 a1 = *(const float4*)(Ag + k0 + 4);
        const float4 b0 = *(const float4*)(Bg + k0);
        const float4 b1 = *(const float4*)(Bg + k0 + 4);
        __syncthreads();   // WAR: previous iter's LDS reads done before overwrite
        As[kOff + 0][mrow] = a0.x; As[kOff + 1][mrow] = a0.y;
        As[kOff + 2][mrow] = a0.z; As[kOff + 3][mrow] = a0.w;
        As[kOff + 4][mrow] = a1.x; As[kOff + 5][mrow] = a1.y;
        As[kOff + 6][mrow] = a1.z; As[kOff + 7][mrow] = a1.w;
        Bs[kOff + 0][mrow] = b0.x; Bs[kOff + 1][mrow] = b0.y;
        Bs[kOff + 2][mrow] = b0.z; Bs[kOff + 3][mrow] = b0.w;
        Bs[kOff + 4][mrow] = b1.x; Bs[kOff + 5][mrow] = b1.y;
        Bs[kOff + 6][mrow] = b1.z; Bs[kOff + 7][mrow] = b1.w;
        __syncthreads();
#pragma unroll
        for (int kk = 0; kk < BK; kk++) {
            const float4 av0 = *(const float4*)&As[kk][ty * 8];
            const float4 av1 = *(const float4*)&As[kk][ty * 8 + 4];
            const float4 bv0 = *(const float4*)&Bs[kk][tx * 8];
            const float4 bv1 = *(const float4*)&Bs[kk][tx * 8 + 4];
            float a[8] = {av0.x, av0.y, av0.z, av0.w, av1.x, av1.y, av1.z, av1.w};
            float b[8] = {bv0.x, bv0.y, bv0.z, bv0.w, bv1.x, bv1.y, bv1.z, bv1.w};
#pragma unroll
            for (int i = 0; i < 8; i++)
#pragma unroll
                for (int j = 0; j < 8; j++)
                    acc[i][j] = fmaf(a[i], b[j], acc[i][j]);
        }
    }

    const long long crow = (long long)blockIdx.y * BM + ty * 8;
    const long long ccol = (long long)blockIdx.x * BN + tx * 8;
#pragma unroll
    for (int i = 0; i < 8; i++) {
        float* cp = C + (crow + i) * N + ccol;
        if (EPI == 0) {
            *(float4*)(cp)     = make_float4(acc[i][0], acc[i][1], acc[i][2], acc[i][3]);
            *(float4*)(cp + 4) = make_float4(acc[i][4], acc[i][5], acc[i][6], acc[i][7]);
        } else {
            const float* ep = E + (crow + i) * N + ccol;
            const float4 e0 = *(const float4*)(ep);
            const float4 e1 = *(const float4*)(ep + 4);
            float d0 = e0.x - acc[i][0], d1 = e0.y - acc[i][1];
            float d2 = e0.z - acc[i][2], d3 = e0.w - acc[i][3];
            float d4 = e1.x - acc[i][4], d5 = e1.y - acc[i][5];
            float d6 = e1.z - acc[i][6], d7 = e1.w - acc[i][7];
            *(float4*)(cp)     = make_float4(d0 * d0, d1 * d1, d2 * d2, d3 * d3);
            *(float4*)(cp + 4) = make_float4(d4 * d4, d5 * d5, d6 * d6, d7 * d7);
        }
    }
}

// in-place row softmax over 2048 cols: p = softmax(p * scale)
__global__ __launch_bounds__(256)
void softmax_rows(float* __restrict__ P, float scale)
{
    float* p = P + (long long)blockIdx.x * 2048;
    const int tid = threadIdx.x;

    const float4 x0 = *(const float4*)(p + tid * 8);
    const float4 x1 = *(const float4*)(p + tid * 8 + 4);
    float v[8] = {x0.x, x0.y, x0.z, x0.w, x1.x, x1.y, x1.z, x1.w};

    float m = -1e30f;
#pragma unroll
    for (int j = 0; j < 8; j++) { v[j] *= scale; m = fmaxf(m, v[j]); }
#pragma unroll
    for (int off = 32; off; off >>= 1) m = fmaxf(m, __shfl_xor(m, off));

    __shared__ float smax[4];
    __shared__ float ssum[4];
    const int wid = tid >> 6, lane = tid & 63;
    if (lane == 0) smax[wid] = m;
    __syncthreads();
    m = fmaxf(fmaxf(smax[0], smax[1]), fmaxf(smax[2], smax[3]));

    float s = 0.f;
#pragma unroll
    for (int j = 0; j < 8; j++) { v[j] = __expf(v[j] - m); s += v[j]; }
#pragma unroll
    for (int off = 32; off; off >>= 1) s += __shfl_xor(s, off);
    if (lane == 0) ssum[wid] = s;
    __syncthreads();
    const float inv = 1.f / (ssum[0] + ssum[1] + ssum[2] + ssum[3]);

    *(float4*)(p + tid * 8)     = make_float4(v[0] * inv, v[1] * inv, v[2] * inv, v[3] * inv);
    *(float4*)(p + tid * 8 + 4) = make_float4(v[4] * inv, v[5] * inv, v[6] * inv, v[7] * inv);
}

extern "C" void kernel_launch(void* const* d_in, const int* in_sizes, int n_in,
                              void* d_out, int out_size, void* d_ws, size_t ws_size,
                              hipStream_t stream)
{
    const float* x   = (const float*)d_in[0];
    const float* Wq1 = (const float*)d_in[1];
    const float* Wk1 = (const float*)d_in[2];
    const float* Wq2 = (const float*)d_in[3];
    const float* Wk2 = (const float*)d_in[4];
    const float* Wv  = (const float*)d_in[5];
    const float* W1  = (const float*)d_in[6];
    const float* W2  = (const float*)d_in[7];
    float* out = (float*)d_out;

    const int H = 8, S = 2048, D = 2048;
    const int MS = H * S;                      // 16384 rows total
    const long long SS = (long long)S * S;     // per-head matrix elems
    const long long SD = (long long)S * D;

    float* Q  = (float*)d_ws;                  // 134 MB each
    float* Kb = Q  + (size_t)MS * D;
    float* Ab = Kb + (size_t)MS * D;
    float* Sb = Ab + (size_t)MS * D;           // total 537 MB of d_ws

    const float scale = 1.0f / sqrtf((float)S);

    dim3 blk(256);
    dim3 gFull(D / BN, MS / BM, 1);            // shared-weight GEMMs, M=16384
    dim3 gHead(S / BN, S / BM, H);             // per-head batched GEMMs
    dim3 gSm(MS);

    // ---- pass 1: a1 = softmax(q1 k1^T), score1 = a1 W1^T ----
    gemm_abt<0><<<gFull, blk, 0, stream>>>(x,  Wq1, Q,  nullptr, MS, D, D, 0, 0, 0);
    gemm_abt<0><<<gFull, blk, 0, stream>>>(x,  Wk1, Kb, nullptr, MS, D, D, 0, 0, 0);
    gemm_abt<0><<<gHead, blk, 0, stream>>>(Q,  Kb,  Ab, nullptr, S,  S, D, SS, SS, SS);
    softmax_rows<<<gSm, blk, 0, stream>>>(Ab, scale);
    gemm_abt<0><<<gFull, blk, 0, stream>>>(Ab, W1,  Sb, nullptr, MS, S, S, 0, 0, 0);

    // ---- pass 2: a2 = softmax(q2 k2^T), circle = (score1 - a2 W2^T)^2 ----
    gemm_abt<0><<<gFull, blk, 0, stream>>>(x,  Wq2, Q,  nullptr, MS, D, D, 0, 0, 0);
    gemm_abt<0><<<gFull, blk, 0, stream>>>(x,  Wk2, Kb, nullptr, MS, D, D, 0, 0, 0);
    gemm_abt<0><<<gHead, blk, 0, stream>>>(Q,  Kb,  Ab, nullptr, S,  S, D, SS, SS, SS);
    softmax_rows<<<gSm, blk, 0, stream>>>(Ab, scale);
    gemm_abt<1><<<gFull, blk, 0, stream>>>(Ab, W2,  Sb, Sb, MS, S, S, 0, 0, 0);

    // ---- v^T then out = circle @ v ----
    // vT[h,d,t] = sum_e Wv[d,e] x[h,t,e]  (A=Wv shared, B=x per head) -> into Q
    gemm_abt<0><<<gHead, blk, 0, stream>>>(Wv, x,   Q,  nullptr, D, S, D, 0, SD, SS);
    // out[h,s,d] = sum_t circle[h,s,t] vT[h,d,t]
    gemm_abt<0><<<gHead, blk, 0, stream>>>(Sb, Q,   out, nullptr, S, D, S, SS, SS, SD);
}

// Round 2
// 2354.894 us; speedup vs baseline: 7.0819x; 7.0819x over previous
//
#include <hip/hip_runtime.h>
#include <math.h>

typedef unsigned short u16;
typedef __bf16 bf16x8 __attribute__((ext_vector_type(8)));
typedef float floatx4 __attribute__((ext_vector_type(4)));

__device__ __forceinline__ u16 f2bf(float f) {
    unsigned int u = __float_as_uint(f);
    u += 0x7FFFu + ((u >> 16) & 1u);          // round-to-nearest-even
    return (u16)(u >> 16);
}

__device__ __forceinline__ void async_load16(const void* g, void* l) {
    __builtin_amdgcn_global_load_lds(
        (const __attribute__((address_space(1))) unsigned int*)g,
        (__attribute__((address_space(3))) unsigned int*)l, 16, 0, 0);
}

#define BM 128
#define BN 128
#define BK 32

// C[M,N] = A[M,K] @ B[N,K]^T, A/B bf16 (u16 bits), fp32 accumulate.
// OUT_BF16: store C as bf16 bits, else fp32.
// EPI: C = (E - acc)^2  (E fp32 read at same coords)
// blockIdx.z batches via element strides sA/sB/sC/sE (0 -> shared operand).
template<int OUT_BF16, int EPI>
__global__ __launch_bounds__(256)
void gemm_mfma(const u16* __restrict__ A, const u16* __restrict__ B,
               void* __restrict__ Cv, const float* __restrict__ E,
               int N, int K,
               long long sA, long long sB, long long sC, long long sE)
{
    __shared__ u16 As[BM * BK];   // 8 KB, row-major [row][k], k-chunks XOR-swizzled
    __shared__ u16 Bs[BN * BK];   // 8 KB

    const long long z = blockIdx.z;
    A += z * sA;
    B += z * sB;

    const int tid  = threadIdx.x;
    const int w    = tid >> 6;
    const int lane = tid & 63;

    // ---- staging addresses (global_load_lds: LDS dest is lane-ordered) ----
    // LDS row r slot s holds global k-chunk s ^ ((r>>2)&3); here (r>>2)&3 == lane>>4.
    const int srow = w * 16 + (lane >> 2);
    const int skp  = ((lane & 3) ^ (lane >> 4)) * 8;     // swizzled global k-chunk
    const u16* Ag = A + ((long long)blockIdx.y * BM + srow) * K + skp;
    const u16* Bg = B + ((long long)blockIdx.x * BN + srow) * K + skp;
    u16* AsP0 = &As[w * 512 + lane * 8];                 // == srow*BK + (lane&3)*8
    u16* AsP1 = AsP0 + 64 * BK;                          // rows +64
    u16* BsP0 = &Bs[w * 512 + lane * 8];
    u16* BsP1 = BsP0 + 64 * BK;
    const long long rstep = (long long)64 * K;

    // ---- compute-side fragment addressing ----
    const int wm   = (w >> 1) * 64, wn = (w & 1) * 64;   // wave 2x2 in 128x128
    const int frow = lane & 15, quad = lane >> 4;
    const int rsw  = (frow >> 2) & 3;                    // row's swizzle key

    floatx4 acc[4][4];
#pragma unroll
    for (int i = 0; i < 4; i++)
#pragma unroll
        for (int j = 0; j < 4; j++) acc[i][j] = (floatx4)0.0f;

    for (int k0 = 0; k0 < K; k0 += BK) {
        __syncthreads();                         // prev iter's LDS reads done
        async_load16(Ag + k0,         AsP0);
        async_load16(Ag + k0 + rstep, AsP1);
        async_load16(Bg + k0,         BsP0);
        async_load16(Bg + k0 + rstep, BsP1);
        __syncthreads();                         // drains vmcnt -> data visible

        union { int4 i4; bf16x8 v; } a[4], b[4];
#pragma unroll
        for (int i = 0; i < 4; i++)
            a[i].i4 = *(const int4*)&As[(wm + 16 * i + frow) * BK + ((quad ^ rsw) * 8)];
#pragma unroll
        for (int j = 0; j < 4; j++)
            b[j].i4 = *(const int4*)&Bs[(wn + 16 * j + frow) * BK + ((quad ^ rsw) * 8)];
#pragma unroll
        for (int i = 0; i < 4; i++)
#pragma unroll
            for (int j = 0; j < 4; j++)
                acc[i][j] = __builtin_amdgcn_mfma_f32_16x16x32_bf16(
                    a[i].v, b[j].v, acc[i][j], 0, 0, 0);
    }

    // ---- epilogue: C/D layout col=lane&15, row=quad*4+reg ----
    const long long crow0 = (long long)blockIdx.y * BM + wm + quad * 4;
    const long long ccol0 = (long long)blockIdx.x * BN + wn + frow;
    u16*   Cb = (u16*)Cv   + z * sC;
    float* Cf = (float*)Cv + z * sC;
    const float* Ep = EPI ? (E + z * sE) : nullptr;
#pragma unroll
    for (int i = 0; i < 4; i++) {
#pragma unroll
        for (int r = 0; r < 4; r++) {
            const long long gr = crow0 + 16 * i + r;
#pragma unroll
            for (int j = 0; j < 4; j++) {
                const long long gc = ccol0 + 16 * j;
                float v = acc[i][j][r];
                if (EPI) {
                    const float e = Ep[gr * (long long)N + gc];
                    const float d = e - v;
                    v = d * d;
                }
                if (OUT_BF16) Cb[gr * (long long)N + gc] = f2bf(v);
                else          Cf[gr * (long long)N + gc] = v;
            }
        }
    }
}

// row softmax over 2048 cols: O = bf16(softmax(P * scale)), P fp32
__global__ __launch_bounds__(256)
void softmax_bf16(const float* __restrict__ P, u16* __restrict__ O, float scale)
{
    const long long rb = (long long)blockIdx.x * 2048;
    const float* p = P + rb;
    const int tid = threadIdx.x;

    const float4 x0 = *(const float4*)(p + tid * 8);
    const float4 x1 = *(const float4*)(p + tid * 8 + 4);
    float v[8] = {x0.x, x0.y, x0.z, x0.w, x1.x, x1.y, x1.z, x1.w};

    float m = -1e30f;
#pragma unroll
    for (int j = 0; j < 8; j++) { v[j] *= scale; m = fmaxf(m, v[j]); }
#pragma unroll
    for (int off = 32; off; off >>= 1) m = fmaxf(m, __shfl_xor(m, off));

    __shared__ float smax[4];
    __shared__ float ssum[4];
    const int wid = tid >> 6, lane = tid & 63;
    if (lane == 0) smax[wid] = m;
    __syncthreads();
    m = fmaxf(fmaxf(smax[0], smax[1]), fmaxf(smax[2], smax[3]));

    float s = 0.f;
#pragma unroll
    for (int j = 0; j < 8; j++) { v[j] = __expf(v[j] - m); s += v[j]; }
#pragma unroll
    for (int off = 32; off; off >>= 1) s += __shfl_xor(s, off);
    if (lane == 0) ssum[wid] = s;
    __syncthreads();
    const float inv = 1.f / (ssum[0] + ssum[1] + ssum[2] + ssum[3]);

    unsigned int p0 = f2bf(v[0] * inv) | ((unsigned int)f2bf(v[1] * inv) << 16);
    unsigned int p1 = f2bf(v[2] * inv) | ((unsigned int)f2bf(v[3] * inv) << 16);
    unsigned int p2 = f2bf(v[4] * inv) | ((unsigned int)f2bf(v[5] * inv) << 16);
    unsigned int p3 = f2bf(v[6] * inv) | ((unsigned int)f2bf(v[7] * inv) << 16);
    *(uint4*)(O + rb + tid * 8) = make_uint4(p0, p1, p2, p3);
}

// fp32 -> bf16 bits, 8 elems/thread; n must be a multiple of 2048
__global__ __launch_bounds__(256)
void cast_bf16(const float* __restrict__ S, u16* __restrict__ D)
{
    const long long i = ((long long)blockIdx.x * 256 + threadIdx.x) * 8;
    const float4 a = *(const float4*)(S + i);
    const float4 b = *(const float4*)(S + i + 4);
    unsigned int p0 = f2bf(a.x) | ((unsigned int)f2bf(a.y) << 16);
    unsigned int p1 = f2bf(a.z) | ((unsigned int)f2bf(a.w) << 16);
    unsigned int p2 = f2bf(b.x) | ((unsigned int)f2bf(b.y) << 16);
    unsigned int p3 = f2bf(b.z) | ((unsigned int)f2bf(b.w) << 16);
    *(uint4*)(D + i) = make_uint4(p0, p1, p2, p3);
}

extern "C" void kernel_launch(void* const* d_in, const int* in_sizes, int n_in,
                              void* d_out, int out_size, void* d_ws, size_t ws_size,
                              hipStream_t stream)
{
    const float* x   = (const float*)d_in[0];
    const float* Wq1 = (const float*)d_in[1];
    const float* Wk1 = (const float*)d_in[2];
    const float* Wq2 = (const float*)d_in[3];
    const float* Wk2 = (const float*)d_in[4];
    const float* Wv  = (const float*)d_in[5];
    const float* W1  = (const float*)d_in[6];
    const float* W2  = (const float*)d_in[7];
    float* out = (float*)d_out;

    const int S = 2048, D = 2048;
    const int MS = 8 * S;                          // 16384
    const long long SS = (long long)S * S;         // 4,194,304
    const long long SD = (long long)S * D;

    // ---- workspace layout (bf16 stored as u16 bits) ----
    u16* xb  = (u16*)d_ws;                         // [MS, D]           67.1 MB
    u16* wb  = xb + (size_t)MS * D;                // 7 x [2048,2048]   58.7 MB
    u16* wq1 = wb + 0 * SS; u16* wk1 = wb + 1 * SS;
    u16* wq2 = wb + 2 * SS; u16* wk2 = wb + 3 * SS;
    u16* wv  = wb + 4 * SS; u16* w1  = wb + 5 * SS; u16* w2 = wb + 6 * SS;
    u16* Qb  = wb + 7 * SS;                        // [MS, D]           67.1 MB
    u16* Kb  = Qb + (size_t)MS * D;                // [MS, D]           67.1 MB
    float* Ab = (float*)(Kb + (size_t)MS * D);     // fp32 logits      134.2 MB
    float* S1 = Ab + (size_t)MS * D;               // fp32 score1      134.2 MB
    // aliases (sequentially safe):
    u16* Pb = Qb;          // bf16 probs overwrite Q after QK^T consumed it
    u16* Cb = (u16*)Ab;    // bf16 circle overwrites logits
    u16* Vt = Kb;          // bf16 v^T overwrites K

    const float scale = 1.0f / sqrtf((float)S);

    dim3 blk(256);
    dim3 gFull(D / BN, MS / BM, 1);   // shared-weight GEMMs (M=16384)
    dim3 gHead(S / BN, S / BM, 8);    // per-head batched GEMMs
    dim3 gSm(MS);

    // ---- casts ----
    cast_bf16<<<dim3((MS * (long long)D) / 2048), blk, 0, stream>>>(x, xb);
    cast_bf16<<<dim3(SS / 2048), blk, 0, stream>>>(Wq1, wq1);
    cast_bf16<<<dim3(SS / 2048), blk, 0, stream>>>(Wk1, wk1);
    cast_bf16<<<dim3(SS / 2048), blk, 0, stream>>>(Wq2, wq2);
    cast_bf16<<<dim3(SS / 2048), blk, 0, stream>>>(Wk2, wk2);
    cast_bf16<<<dim3(SS / 2048), blk, 0, stream>>>(Wv, wv);
    cast_bf16<<<dim3(SS / 2048), blk, 0, stream>>>(W1, w1);
    cast_bf16<<<dim3(SS / 2048), blk, 0, stream>>>(W2, w2);

    // ---- pass 1 ----
    gemm_mfma<1,0><<<gFull, blk, 0, stream>>>(xb, wq1, Qb, nullptr, D, D, 0, 0, 0, 0);
    gemm_mfma<1,0><<<gFull, blk, 0, stream>>>(xb, wk1, Kb, nullptr, D, D, 0, 0, 0, 0);
    gemm_mfma<0,0><<<gHead, blk, 0, stream>>>(Qb, Kb, Ab, nullptr, S, D, SS, SS, SS, 0);
    softmax_bf16<<<gSm, blk, 0, stream>>>(Ab, Pb, scale);
    gemm_mfma<0,0><<<gFull, blk, 0, stream>>>(Pb, w1, S1, nullptr, S, S, 0, 0, 0, 0);

    // ---- pass 2 ----
    gemm_mfma<1,0><<<gFull, blk, 0, stream>>>(xb, wq2, Qb, nullptr, D, D, 0, 0, 0, 0);
    gemm_mfma<1,0><<<gFull, blk, 0, stream>>>(xb, wk2, Kb, nullptr, D, D, 0, 0, 0, 0);
    gemm_mfma<0,0><<<gHead, blk, 0, stream>>>(Qb, Kb, Ab, nullptr, S, D, SS, SS, SS, 0);
    softmax_bf16<<<gSm, blk, 0, stream>>>(Ab, Pb, scale);
    // circle = (score1 - P2@W2^T)^2, bf16 out
    gemm_mfma<1,1><<<gFull, blk, 0, stream>>>(Pb, w2, Cb, S1, S, S, 0, 0, 0, 0);

    // ---- v^T and final ----
    // Vt[h,d,t] = sum_e Wv[d,e] x[h,t,e]
    gemm_mfma<1,0><<<gHead, blk, 0, stream>>>(wv, xb, Vt, nullptr, S, D, 0, SD, SS, 0);
    // out[h,s,d] = sum_t circle[h,s,t] Vt[h,d,t]
    gemm_mfma<0,0><<<gHead, blk, 0, stream>>>(Cb, Vt, out, nullptr, D, S, SS, SS, SD, 0);
}